// Round 6
// baseline (404.910 us; speedup 1.0000x reference)
//
#include <hip/hip_runtime.h>
#include <cstdint>

typedef int v4i __attribute__((ext_vector_type(4)));

#define K_DIM 4096
#define BM 256
#define BN 256
#define BK 64
#define NT (K_DIM / BK)          // 64 K-tiles
#define BUFS 32768               // A 16KB + B 16KB per buffer
#define NBUF 4                   // 128 KiB LDS, stage-ahead 3, 2 tiles resident

// ---------------------------------------------------------------------------
// Kernel 0: pack int32 weight -> int8.
// ---------------------------------------------------------------------------
__global__ __launch_bounds__(256) void pack_weight(
    const int* __restrict__ w32, int8_t* __restrict__ w8, int total16)
{
    const int i = blockIdx.x * 256 + threadIdx.x;
    if (i >= total16) return;
    const v4i* src = reinterpret_cast<const v4i*>(w32) + i * 4;
    v4i out;
#pragma unroll
    for (int j = 0; j < 4; ++j) {
        const v4i v = src[j];
        out[j] = (v.x & 0xff) | ((v.y & 0xff) << 8) |
                 ((v.z & 0xff) << 16) | ((unsigned)(v.w & 0xff) << 24);
    }
    reinterpret_cast<v4i*>(w8)[i] = out;
}

// ---------------------------------------------------------------------------
// Kernel 1: per-row symmetric int8 quantization (verified).
// ---------------------------------------------------------------------------
__global__ __launch_bounds__(256) void quant_rows(
    const float* __restrict__ x, int8_t* __restrict__ q,
    float* __restrict__ scales)
{
    const int row = blockIdx.x;
    const int t   = threadIdx.x;
    const float4* xr4 = reinterpret_cast<const float4*>(x + (size_t)row * K_DIM);

    float4 v[4];
    float m = 0.0f;
#pragma unroll
    for (int i = 0; i < 4; ++i) {
        v[i] = xr4[i * 256 + t];
        m = fmaxf(m, fmaxf(fmaxf(fabsf(v[i].x), fabsf(v[i].y)),
                           fmaxf(fabsf(v[i].z), fabsf(v[i].w))));
    }
#pragma unroll
    for (int off = 32; off >= 1; off >>= 1)
        m = fmaxf(m, __shfl_xor(m, off, 64));

    __shared__ float wmax[4];
    if ((t & 63) == 0) wmax[t >> 6] = m;
    __syncthreads();
    const float am = fmaxf(fmaxf(wmax[0], wmax[1]), fmaxf(wmax[2], wmax[3]));
    const float s  = fmaxf(am / 127.0f, 1e-8f);
    if (t == 0) scales[row] = s;

    int* qi = reinterpret_cast<int*>(q + (size_t)row * K_DIM);
#pragma unroll
    for (int i = 0; i < 4; ++i) {
        const float e[4] = {v[i].x, v[i].y, v[i].z, v[i].w};
        unsigned packed = 0;
#pragma unroll
        for (int j = 0; j < 4; ++j) {
            float r = rintf(e[j] / s);
            r = fminf(fmaxf(r, -127.0f), 127.0f);
            packed |= ((unsigned)((int)r & 0xff)) << (8 * j);
        }
        qi[i * 256 + t] = (int)packed;
    }
}

// ---------------------------------------------------------------------------
// Kernel 2: int8 GEMM, 256x256 tile, 4 waves (2Mx2N), wave-tile 128x128,
// ONE wave per SIMD (launch_bounds(256,1) -> up to 512 unified regs/wave).
// B-frags (8 v4i) live in registers for the whole K-tile; A-frags stream
// through a 4-deep ring (2-phase lead); B-next read 1/phase (8-phase lead).
// One barrier + counted vmcnt(8) per K-tile; NBUF=4, stage tile t+3 during t.
//
// Residency invariant (per-wave in-order vmcnt): entering tile t, tiles t and
// t+1 are retired+barrier-visible; t+2's 8 loads in flight. Proof: boundary
// t-1 -> t has outstanding = t+1's 8 (issued t-2) + t+2's 8 (issued t-1);
// vmcnt(8) retires t+1's. Hence phase-6/7 A-next and per-phase B-next reads
// (both target buf[t+1]) are race-free. Overwrite: stage during t writes
// buf[(t+3)&3] = buf[t-1], all of whose reads were value-consumed (and thus
// lgkm-retired) before the t-1 -> t boundary barrier.
// ---------------------------------------------------------------------------
__global__ __launch_bounds__(256, 1) void gemm_i8(
    const int8_t* __restrict__ A,   // [M][K] quantized activations
    const int8_t* __restrict__ B,   // [N][K] packed weight
    const float* __restrict__ sA,   // [M] per-row scales
    const float* __restrict__ wsc,  // [1] weight scale
    float* __restrict__ C,          // [M][N]
    int M, int N)
{
    __shared__ int8_t lds[NBUF * BUFS];   // 128 KiB

    const int t    = threadIdx.x;
    const int lane = t & 63;
    const int w    = t >> 6;        // 0..3
    const int wr   = w >> 1;        // 0..1 -> 128-row half
    const int wc   = w & 1;         // 0..1 -> 128-col half

    // T1: XCD-aware block swizzle (nwg = 512, divisible by 8)
    const int nwg = gridDim.x;
    int bid = blockIdx.x;
    if ((nwg & 7) == 0) bid = (bid & 7) * (nwg >> 3) + (bid >> 3);
    const int ntn  = N / BN;
    const int brow = (bid / ntn) * BM;
    const int bcol = (bid % ntn) * BN;

    // ---- staging: 8 chunks/thread/tile (A:0..3, B:4..7); linear LDS dest,
    // inverse-swizzled global source (verified 0-conflict since R3) ----------
    const int8_t* gsrc[8];
    int ldst[8];
#pragma unroll
    for (int c = 0; c < 4; ++c) {
        const int idx  = c * 256 + t;
        const int row  = idx >> 2;                          // 0..255
        const int colq = (((idx & 3) ^ ((row >> 1) & 3)) << 4);
        gsrc[c]     = A + (size_t)(brow + row) * K_DIM + colq;
        ldst[c]     = idx * 16;
        gsrc[4 + c] = B + (size_t)(bcol + row) * K_DIM + colq;
        ldst[4 + c] = 16384 + idx * 16;
    }

#define GLDS(gp, off) \
    __builtin_amdgcn_global_load_lds( \
        (const __attribute__((address_space(1))) void*)(gp), \
        (__attribute__((address_space(3))) void*)(lds + (off)), 16, 0, 0)

    // ---- swizzled fragment offsets (frag stride 1024 = 16 rows * 64B) ------
    const int l15 = lane & 15;
    const unsigned swz = ((unsigned)((lane >> 4) ^ ((l15 >> 1) & 3))) << 4;
    const unsigned vA = (unsigned)((wr * 128 + l15) * 64) + swz;
    const unsigned vB = 16384u + (unsigned)((wc * 128 + l15) * 64) + swz;

    v4i acc[8][8];
#pragma unroll
    for (int m = 0; m < 8; ++m)
#pragma unroll
        for (int n = 0; n < 8; ++n)
            acc[m][n] = (v4i){0, 0, 0, 0};

    v4i aR[4], Ba[8], Bb[8];

    // ---- prologue: stage tiles 0,1,2 (24 GLDS); retire tiles 0,1 -----------
#pragma unroll
    for (int c = 0; c < 8; ++c) GLDS(gsrc[c],            ldst[c]);
#pragma unroll
    for (int c = 0; c < 8; ++c) GLDS(gsrc[c] + BK,       BUFS + ldst[c]);
#pragma unroll
    for (int c = 0; c < 8; ++c) GLDS(gsrc[c] + 2 * BK, 2 * BUFS + ldst[c]);
    asm volatile("s_waitcnt vmcnt(8)" ::: "memory");
    __builtin_amdgcn_s_barrier();

    // preload tile 0: all 8 B-frags + A-frags 0,1
#pragma unroll
    for (int n = 0; n < 8; ++n) Ba[n] = *(const v4i*)(lds + vB + n * 1024);
    aR[0] = *(const v4i*)(lds + vA);
    aR[1] = *(const v4i*)(lds + vA + 1024);

#define MFMA8(P, BC) do { \
    acc[P][0] = __builtin_amdgcn_mfma_i32_16x16x64_i8(aR[(P)&3], BC[0], acc[P][0], 0,0,0); \
    acc[P][1] = __builtin_amdgcn_mfma_i32_16x16x64_i8(aR[(P)&3], BC[1], acc[P][1], 0,0,0); \
    acc[P][2] = __builtin_amdgcn_mfma_i32_16x16x64_i8(aR[(P)&3], BC[2], acc[P][2], 0,0,0); \
    acc[P][3] = __builtin_amdgcn_mfma_i32_16x16x64_i8(aR[(P)&3], BC[3], acc[P][3], 0,0,0); \
    acc[P][4] = __builtin_amdgcn_mfma_i32_16x16x64_i8(aR[(P)&3], BC[4], acc[P][4], 0,0,0); \
    acc[P][5] = __builtin_amdgcn_mfma_i32_16x16x64_i8(aR[(P)&3], BC[5], acc[P][5], 0,0,0); \
    acc[P][6] = __builtin_amdgcn_mfma_i32_16x16x64_i8(aR[(P)&3], BC[6], acc[P][6], 0,0,0); \
    acc[P][7] = __builtin_amdgcn_mfma_i32_16x16x64_i8(aR[(P)&3], BC[7], acc[P][7], 0,0,0); \
    } while (0)

    // phase P: A-ring read (lead 2), B-next read (lead 8), 1 stage chunk, 8 MFMA
#define PHASE(P, BC, BNX) do { \
    if ((P) <= 5) aR[((P)+2)&3] = *(const v4i*)(bufc + vA + ((P)+2) * 1024); \
    else if (notlast) aR[((P)+2)&3] = *(const v4i*)(bufn + vA + ((P)-6) * 1024); \
    if (notlast) BNX[(P)] = *(const v4i*)(bufn + vB + (P) * 1024); \
    if (more) GLDS(gsrc[(P)] + (size_t)T3 * BK, stoff + ldst[(P)]); \
    MFMA8(P, BC); \
    } while (0)

#define TILE_BODY(T, BC, BNX) do { \
    const int8_t* bufc = lds + cur * BUFS; \
    const int8_t* bufn = lds + ((cur + 1) & 3) * BUFS; \
    const unsigned stoff = (unsigned)(((cur + 3) & 3) * BUFS); \
    const bool more = (T) + 3 < NT; \
    const bool notlast = (T) + 1 < NT; \
    const int T3 = (T) + 3; \
    PHASE(0, BC, BNX); PHASE(1, BC, BNX); PHASE(2, BC, BNX); PHASE(3, BC, BNX); \
    PHASE(4, BC, BNX); PHASE(5, BC, BNX); PHASE(6, BC, BNX); PHASE(7, BC, BNX); \
    if (more)         asm volatile("s_waitcnt vmcnt(8)" ::: "memory"); \
    else              asm volatile("s_waitcnt vmcnt(0)" ::: "memory"); \
    if (notlast) __builtin_amdgcn_s_barrier(); \
    cur = (cur + 1) & 3; \
    } while (0)

    int cur = 0;
    for (int tt = 0; tt < NT; tt += 2) {
        TILE_BODY(tt,     Ba, Bb);   // compute with Ba, prefetch Bb
        TILE_BODY(tt + 1, Bb, Ba);   // compute with Bb, prefetch Ba
    }

    // ---- epilogue: C/D layout col = lane&15, row = (lane>>4)*4 + reg ------
    const float wsv = wsc[0];
#pragma unroll
    for (int m = 0; m < 8; ++m) {
        const int rbase = brow + wr * 128 + m * 16 + (lane >> 4) * 4;
        float sc[4];
#pragma unroll
        for (int j = 0; j < 4; ++j) sc[j] = sA[rbase + j] * wsv;
#pragma unroll
        for (int n = 0; n < 8; ++n) {
            const int col = bcol + wc * 128 + n * 16 + l15;
#pragma unroll
            for (int j = 0; j < 4; ++j)
                C[(size_t)(rbase + j) * N + col] = (float)acc[m][n][j] * sc[j];
        }
    }
#undef GLDS
#undef MFMA8
#undef PHASE
#undef TILE_BODY
}

extern "C" void kernel_launch(void* const* d_in, const int* in_sizes, int n_in,
                              void* d_out, int out_size, void* d_ws, size_t ws_size,
                              hipStream_t stream) {
    const float* x      = (const float*)d_in[0];
    const int*   w32    = (const int*)d_in[1];     // int8 widened to int32
    const float* wscale = (const float*)d_in[2];
    float*       out    = (float*)d_out;

    const int M = in_sizes[0] / K_DIM;   // 8192
    const int N = in_sizes[1] / K_DIM;   // 4096

    int8_t* q      = (int8_t*)d_ws;
    float*  scales = (float*)((char*)d_ws + (size_t)M * K_DIM);
    int8_t* w8     = (int8_t*)((char*)d_ws + (size_t)M * K_DIM + (size_t)M * sizeof(float));

    const int total16 = (N * K_DIM) / 16;
    pack_weight<<<(total16 + 255) / 256, 256, 0, stream>>>(w32, w8, total16);

    quant_rows<<<M, 256, 0, stream>>>(x, q, scales);

    const int nblk = (M / BM) * (N / BN);   // 512
    gemm_i8<<<nblk, 256, 0, stream>>>(q, w8, scales, wscale, out, M, N);
}

// Round 7
// 205.153 us; speedup vs baseline: 1.9737x; 1.9737x over previous
//
#include <hip/hip_runtime.h>
#include <cstdint>

typedef int v4i __attribute__((ext_vector_type(4)));

#define K_DIM 4096
#define QBM 128
#define QBN 256
#define QBK 64
#define NT (K_DIM / QBK)          // 64 K-tiles
#define ATILE (QBM * QBK)         // 8 KiB
#define BTILE (QBN * QBK)         // 16 KiB
#define QBUFS (ATILE + BTILE)     // 24 KiB
#define QNBUF 3                   // 72 KiB LDS -> 2 blocks/CU

// ---------------------------------------------------------------------------
// Kernel 0: fused prep. blocks [0, qrows): per-row int8 quantization of x.
// blocks [qrows, qrows+pblocks): pack int32 weight -> int8. One launch.
// ---------------------------------------------------------------------------
__global__ __launch_bounds__(256) void prep(
    const float* __restrict__ x, int8_t* __restrict__ q,
    float* __restrict__ scales,
    const int* __restrict__ w32, int8_t* __restrict__ w8,
    int qrows, int total16)
{
    const int b = blockIdx.x;
    const int t = threadIdx.x;
    if (b < qrows) {
        // ---- quantize one row of 4096 floats ----
        const float4* xr4 = reinterpret_cast<const float4*>(x + (size_t)b * K_DIM);
        float4 v[4];
        float m = 0.0f;
#pragma unroll
        for (int i = 0; i < 4; ++i) {
            v[i] = xr4[i * 256 + t];
            m = fmaxf(m, fmaxf(fmaxf(fabsf(v[i].x), fabsf(v[i].y)),
                               fmaxf(fabsf(v[i].z), fabsf(v[i].w))));
        }
#pragma unroll
        for (int off = 32; off >= 1; off >>= 1)
            m = fmaxf(m, __shfl_xor(m, off, 64));
        __shared__ float wmax[4];
        if ((t & 63) == 0) wmax[t >> 6] = m;
        __syncthreads();
        const float am = fmaxf(fmaxf(wmax[0], wmax[1]), fmaxf(wmax[2], wmax[3]));
        const float s  = fmaxf(am / 127.0f, 1e-8f);
        if (t == 0) scales[b] = s;
        int* qi = reinterpret_cast<int*>(q + (size_t)b * K_DIM);
#pragma unroll
        for (int i = 0; i < 4; ++i) {
            const float e[4] = {v[i].x, v[i].y, v[i].z, v[i].w};
            unsigned packed = 0;
#pragma unroll
            for (int j = 0; j < 4; ++j) {
                float r = rintf(e[j] / s);
                r = fminf(fmaxf(r, -127.0f), 127.0f);
                packed |= ((unsigned)((int)r & 0xff)) << (8 * j);
            }
            qi[i * 256 + t] = (int)packed;
        }
    } else {
        // ---- pack 16 int32 -> 16 int8 per thread ----
        const int i = (b - qrows) * 256 + t;
        if (i >= total16) return;
        const v4i* src = reinterpret_cast<const v4i*>(w32) + i * 4;
        v4i out;
#pragma unroll
        for (int j = 0; j < 4; ++j) {
            const v4i vv = src[j];
            out[j] = (vv.x & 0xff) | ((vv.y & 0xff) << 8) |
                     ((vv.z & 0xff) << 16) | ((unsigned)(vv.w & 0xff) << 24);
        }
        reinterpret_cast<v4i*>(w8)[i] = out;
    }
}

// ---------------------------------------------------------------------------
// Kernel 1: int8 GEMM, 128x256 block tile, 4 waves (1Mx4N), wave = 128x64.
// NBUF=3 ring (72 KiB LDS -> TWO independent blocks per CU: decorrelated
// barrier domains so one block's MFMA burst hides the other's LDS burst).
// Stage tile t+2 during t (6 GLDS/thread), boundary vmcnt(6) + 1 barrier.
//
// Residency: entering tile t, tile t resident+visible, t+1's 6 loads in
// flight; during t issue t+2's 6. Boundary vmcnt(6) retires t+1's.
// Overwrite: t+2 targets buf[(t+2)%3] = buf[(t-1)%3], whose reads were all
// consumed by t-1's MFMAs before the t-1 -> t barrier.
// ---------------------------------------------------------------------------
__global__ __launch_bounds__(256, 2) void gemm_i8(
    const int8_t* __restrict__ A,   // [M][K] quantized activations
    const int8_t* __restrict__ B,   // [N][K] packed weight
    const float* __restrict__ sA,   // [M] per-row scales
    const float* __restrict__ wsc,  // [1] weight scale
    float* __restrict__ C,          // [M][N]
    int M, int N)
{
    __shared__ int8_t lds[QNBUF * QBUFS];   // 72 KiB

    const int t    = threadIdx.x;
    const int lane = t & 63;
    const int wc   = t >> 6;        // 0..3 -> 64-col slice

    // T1: XCD-aware block swizzle (nwg = 1024, divisible by 8)
    const int nwg = gridDim.x;
    int bid = blockIdx.x;
    if ((nwg & 7) == 0) bid = (bid & 7) * (nwg >> 3) + (bid >> 3);
    const int ntn  = N / QBN;       // 16
    const int brow = (bid / ntn) * QBM;
    const int bcol = (bid % ntn) * QBN;

    // ---- staging: linear LDS dest, inverse-swizzled global src (verified) --
    // A: 2 chunks (idx 0..511, row 0..127); B: 4 chunks (idx 0..1023, row 0..255)
    const int8_t* gsA[2]; int ldA[2];
    const int8_t* gsB[4]; int ldB[4];
#pragma unroll
    for (int c = 0; c < 2; ++c) {
        const int idx = c * 256 + t;
        const int row = idx >> 2;
        const int col = (((idx & 3) ^ ((row >> 1) & 3)) << 4);
        gsA[c] = A + (size_t)(brow + row) * K_DIM + col;
        ldA[c] = idx * 16;
    }
#pragma unroll
    for (int c = 0; c < 4; ++c) {
        const int idx = c * 256 + t;
        const int row = idx >> 2;
        const int col = (((idx & 3) ^ ((row >> 1) & 3)) << 4);
        gsB[c] = B + (size_t)(bcol + row) * K_DIM + col;
        ldB[c] = ATILE + idx * 16;
    }

#define GLDS(gp, off) \
    __builtin_amdgcn_global_load_lds( \
        (const __attribute__((address_space(1))) void*)(gp), \
        (__attribute__((address_space(3))) void*)(lds + (off)), 16, 0, 0)
#define STAGE(bf, tt) do { \
    GLDS(gsA[0] + (size_t)(tt) * QBK, (bf) * QBUFS + ldA[0]); \
    GLDS(gsA[1] + (size_t)(tt) * QBK, (bf) * QBUFS + ldA[1]); \
    GLDS(gsB[0] + (size_t)(tt) * QBK, (bf) * QBUFS + ldB[0]); \
    GLDS(gsB[1] + (size_t)(tt) * QBK, (bf) * QBUFS + ldB[1]); \
    GLDS(gsB[2] + (size_t)(tt) * QBK, (bf) * QBUFS + ldB[2]); \
    GLDS(gsB[3] + (size_t)(tt) * QBK, (bf) * QBUFS + ldB[3]); } while (0)

    // ---- swizzled fragment offsets; frag stride 1024 B (16 rows x 64 B) ----
    const int l15 = lane & 15;
    const unsigned swz = ((unsigned)((lane >> 4) ^ ((l15 >> 1) & 3))) << 4;
    const unsigned vA = (unsigned)(l15 * QBK) + swz;                       // A row l15
    const unsigned vB = (unsigned)(ATILE + (wc * 64 + l15) * QBK) + swz;   // B row wc*64+l15

    v4i acc[8][4];
#pragma unroll
    for (int m = 0; m < 8; ++m)
#pragma unroll
        for (int n = 0; n < 4; ++n)
            acc[m][n] = (v4i){0, 0, 0, 0};

    // ---- prologue: stage tiles 0,1; retire tile 0 --------------------------
    STAGE(0, 0);
    STAGE(1, 1);
    asm volatile("s_waitcnt vmcnt(6)" ::: "memory");
    __builtin_amdgcn_s_barrier();

    int cur = 0;
    for (int tt = 0; tt < NT; ++tt) {
        const int8_t* bufc = lds + cur * QBUFS;
        int nx2 = cur + 2; if (nx2 >= QNBUF) nx2 -= QNBUF;
        const bool more    = tt + 2 < NT;
        const bool notlast = tt + 1 < NT;

        // stage tile t+2 first so loads issue under this tile's compute
        if (more) STAGE(nx2, tt + 2);

        // fragment reads (compiler-scheduled, counted lgkmcnt before MFMA use)
        v4i af[8], bf[4];
#pragma unroll
        for (int m = 0; m < 8; ++m)
            af[m] = *(const v4i*)(bufc + vA + m * 1024);
#pragma unroll
        for (int n = 0; n < 4; ++n)
            bf[n] = *(const v4i*)(bufc + vB + n * 1024);

        __builtin_amdgcn_s_setprio(1);
#pragma unroll
        for (int m = 0; m < 8; ++m)
#pragma unroll
            for (int n = 0; n < 4; ++n)
                acc[m][n] = __builtin_amdgcn_mfma_i32_16x16x64_i8(
                    af[m], bf[n], acc[m][n], 0, 0, 0);
        __builtin_amdgcn_s_setprio(0);

        // boundary: counted vmcnt (never 0 in steady state) + one barrier
        if (more)         asm volatile("s_waitcnt vmcnt(6)" ::: "memory");
        else if (notlast) asm volatile("s_waitcnt vmcnt(0)" ::: "memory");
        if (notlast) __builtin_amdgcn_s_barrier();

        cur = cur + 1; if (cur >= QNBUF) cur -= QNBUF;
    }

    // ---- epilogue: C/D layout col = lane&15, row = (lane>>4)*4 + reg -------
    const float wsv = wsc[0];
#pragma unroll
    for (int m = 0; m < 8; ++m) {
        const int rbase = brow + m * 16 + (lane >> 4) * 4;
        float sc[4];
#pragma unroll
        for (int j = 0; j < 4; ++j) sc[j] = sA[rbase + j] * wsv;
#pragma unroll
        for (int n = 0; n < 4; ++n) {
            const int col = bcol + wc * 64 + n * 16 + l15;
#pragma unroll
            for (int j = 0; j < 4; ++j)
                C[(size_t)(rbase + j) * N + col] = (float)acc[m][n][j] * sc[j];
        }
    }
#undef GLDS
#undef STAGE
}

extern "C" void kernel_launch(void* const* d_in, const int* in_sizes, int n_in,
                              void* d_out, int out_size, void* d_ws, size_t ws_size,
                              hipStream_t stream) {
    const float* x      = (const float*)d_in[0];
    const int*   w32    = (const int*)d_in[1];     // int8 widened to int32
    const float* wscale = (const float*)d_in[2];
    float*       out    = (float*)d_out;

    const int M = in_sizes[0] / K_DIM;   // 8192
    const int N = in_sizes[1] / K_DIM;   // 4096

    int8_t* q      = (int8_t*)d_ws;
    float*  scales = (float*)((char*)d_ws + (size_t)M * K_DIM);
    int8_t* w8     = (int8_t*)((char*)d_ws + (size_t)M * K_DIM + (size_t)M * sizeof(float));

    const int total16 = (N * K_DIM) / 16;           // 1,048,576
    const int pblocks = (total16 + 255) / 256;      // 4096
    prep<<<M + pblocks, 256, 0, stream>>>(x, q, scales, w32, w8, M, total16);

    const int nblk = (M / QBM) * (N / QBN);         // 64 * 16 = 1024
    gemm_i8<<<nblk, 256, 0, stream>>>(q, w8, scales, wscale, out, M, N);
}